// Round 8
// baseline (286.579 us; speedup 1.0000x reference)
//
#include <hip/hip_runtime.h>
#include <hip/hip_bf16.h>

// ---- problem constants ----
#define N_GAUSS 4096
#define N_PTS   32768
#define BLOCK   256
#define NSPLIT  16
#define NBLK_PT 128                 // 128 x 256 = 32768 points
#define GSTRIDE 32                  // floats per packed gaussian = 8 x float4
#define NCELL   4096                // 16^3 morton cells

#define SH_C0  0.28209479177387814f
#define SH_C1  0.4886025119029199f

// Workspace layout (float index):
#define WS_GP     0                          // 4096*32 = 131072 floats (512 KB)
#define WS_TICKET 131072                     // int[128] (padded to 256)
#define WS_SPTS   131328                     // float4[32768] = 131072 floats
#define WS_PART   262400                     // u64[2048*256] = 1048576 floats
// total 1,310,976 floats = 5.24 MB (same footprint as round 7 — known OK)

__device__ __forceinline__ int expand4(int b) {
    return (b & 1) | ((b & 2) << 2) | ((b & 4) << 4) | ((b & 8) << 6);
}

union F2U { float2 f2; unsigned long long u; };

// ---------------------------------------------------------------------------
// Node A: ONE block, 1024 threads. Everything except the main eval:
//   - zero per-pb tickets
//   - gaussian prep -> gp (8 x float4 per gaussian)
//   - point binning -> LDS cell ids -> LDS histogram -> exclusive scan
//   - scatter points into sorted float4 (xyz + bitcast orig idx)
// Gaussian record: q0=(cx,cy,cz,Tg) q1=(pxx,pxy,pxz,pyy) q2=(pyz,pzz,lnop,0)
//                  q3..q6 = SH coeffs (constants pre-multiplied), q7 = pad
// ---------------------------------------------------------------------------
__global__ __launch_bounds__(1024) void setup_kernel(
    const float* __restrict__ pts, const float* __restrict__ xyz,
    const float* __restrict__ sh_dc, const float* __restrict__ sh_rest,
    const float* __restrict__ scaling, const float* __restrict__ rotation,
    const float* __restrict__ opl, float* __restrict__ gp,
    int* __restrict__ ticket, float4* __restrict__ spts)
{
    __shared__ unsigned short s_cell[N_PTS];   // 64 KB
    __shared__ int s_hist[NCELL];              // 16 KB
    __shared__ int s_scan[1024];               // 4 KB
    const int t = threadIdx.x;

    if (t < 128) ticket[t] = 0;

    // ---- gaussian prep (4 per thread) ----
    for (int g = t; g < N_GAUSS; g += 1024) {
        float s0 = scaling[3*g+0], s1 = scaling[3*g+1], s2 = scaling[3*g+2];
        float i0 = __expf(-2.0f * s0);
        float i1 = __expf(-2.0f * s1);
        float i2 = __expf(-2.0f * s2);
        float maxs2 = __expf(2.0f * fmaxf(s0, fmaxf(s1, s2)));

        float r = rotation[4*g+0], x = rotation[4*g+1];
        float y = rotation[4*g+2], z = rotation[4*g+3];
        float n = rsqrtf(r*r + x*x + y*y + z*z);
        r *= n; x *= n; y *= n; z *= n;
        float R00 = 1.f - 2.f*(y*y + z*z), R01 = 2.f*(x*y - r*z), R02 = 2.f*(x*z + r*y);
        float R10 = 2.f*(x*y + r*z), R11 = 1.f - 2.f*(x*x + z*z), R12 = 2.f*(y*z - r*x);
        float R20 = 2.f*(x*z - r*y), R21 = 2.f*(y*z + r*x), R22 = 1.f - 2.f*(x*x + y*y);

        float pxx = 0.5f*(R00*R00*i0 + R01*R01*i1 + R02*R02*i2);
        float pxy = 0.5f*(R00*R10*i0 + R01*R11*i1 + R02*R12*i2);
        float pxz = 0.5f*(R00*R20*i0 + R01*R21*i1 + R02*R22*i2);
        float pyy = 0.5f*(R10*R10*i0 + R11*R11*i1 + R12*R12*i2);
        float pyz = 0.5f*(R10*R20*i0 + R11*R21*i1 + R12*R22*i2);
        float pzz = 0.5f*(R20*R20*i0 + R21*R21*i1 + R22*R22*i2);

        float op   = 1.f / (1.f + __expf(-opl[g]));
        float lnop = __logf(op);
        // d2 > Tg => w < e^-16 ~ 1.1e-7 ; dropped total ~2e-3 << 4.1e-2 threshold
        float Tg   = 2.0f * maxs2 * (lnop + 16.0f);

        float* G = gp + (size_t)g * GSTRIDE;
        G[0] = xyz[3*g+0]; G[1] = xyz[3*g+1]; G[2] = xyz[3*g+2]; G[3] = Tg;
        G[4] = pxx; G[5] = pxy; G[6] = pxz; G[7] = pyy;
        G[8] = pyz; G[9] = pzz; G[10] = lnop; G[11] = 0.f;

        const float* sr = sh_rest + (size_t)g * 15;
        G[12] =  SH_C0 * sh_dc[g];
        G[13] = -SH_C1 * sr[0];
        G[14] =  SH_C1 * sr[1];
        G[15] = -SH_C1 * sr[2];
        G[16] =  1.0925484305920792f  * sr[3];
        G[17] = -1.0925484305920792f  * sr[4];
        G[18] =  0.31539156525252005f * sr[5];
        G[19] = -1.0925484305920792f  * sr[6];
        G[20] =  0.5462742152960396f  * sr[7];
        G[21] = -0.5900435899266435f  * sr[8];
        G[22] =  2.890611442640554f   * sr[9];
        G[23] = -0.4570457994644658f  * sr[10];
        G[24] =  0.3731763325901154f  * sr[11];
        G[25] = -0.4570457994644658f  * sr[12];
        G[26] =  1.445305721320277f   * sr[13];
        G[27] = -0.5900435899266435f  * sr[14];
        G[28] = 0.f; G[29] = 0.f; G[30] = 0.f; G[31] = 0.f;
    }

    // ---- bin points ----
    #pragma unroll
    for (int i = 0; i < 4; ++i) s_hist[t + i * 1024] = 0;
    __syncthreads();
    for (int p = t; p < N_PTS; p += 1024) {
        float x = pts[3*p+0], y = pts[3*p+1], z = pts[3*p+2];
        int cx = min(15, max(0, (int)((x + 3.2f) * 2.5f)));
        int cy = min(15, max(0, (int)((y + 3.2f) * 2.5f)));
        int cz = min(15, max(0, (int)((z + 3.2f) * 2.5f)));
        int cell = expand4(cx) | (expand4(cy) << 1) | (expand4(cz) << 2);
        s_cell[p] = (unsigned short)cell;
        atomicAdd(&s_hist[cell], 1);
    }
    __syncthreads();

    // ---- exclusive scan over 4096 counts ----
    int b = t * 4;
    int c0 = s_hist[b], c1 = s_hist[b+1], c2 = s_hist[b+2], c3 = s_hist[b+3];
    int s = c0 + c1 + c2 + c3;
    s_scan[t] = s;
    __syncthreads();
    for (int off = 1; off < 1024; off <<= 1) {
        int v = (t >= off) ? s_scan[t - off] : 0;
        __syncthreads();
        s_scan[t] += v;
        __syncthreads();
    }
    int excl = s_scan[t] - s;
    s_hist[b] = excl; s_hist[b+1] = excl + c0;
    s_hist[b+2] = excl + c0 + c1; s_hist[b+3] = excl + c0 + c1 + c2;
    __syncthreads();

    // ---- scatter sorted points ----
    for (int p = t; p < N_PTS; p += 1024) {
        float x = pts[3*p+0], y = pts[3*p+1], z = pts[3*p+2];
        int pos = atomicAdd(&s_hist[s_cell[p]], 1);
        spts[pos] = make_float4(x, y, z, __int_as_float(p));
    }
}

// ---------------------------------------------------------------------------
// Node B: main eval + fused last-block reduction.
// Block = (256 sorted points) x (1/16 gaussians). AABB cull -> stage surviving
// records into LDS (coalesced) -> pipelined eval from LDS -> agent-scope
// partial store -> ticket; the 16th block per pb gathers and writes out.
// ---------------------------------------------------------------------------
__global__ __launch_bounds__(BLOCK, 4) void gauss_kernel(
    const float4* __restrict__ spts, const float4* __restrict__ gp4,
    unsigned long long* __restrict__ part, int* __restrict__ ticket,
    float* __restrict__ out)
{
    __shared__ float4 s_rec[BLOCK * 8];        // 32 KB staged records
    __shared__ float s_min[4][3], s_max[4][3];
    __shared__ int s_nact, s_last;
    __shared__ int s_act[BLOCK];

    const int tid = threadIdx.x;
    const int pb  = blockIdx.x & (NBLK_PT - 1);
    const int seg = blockIdx.x >> 7;
    float4 P = spts[pb * 256 + tid];
    const float px = P.x, py = P.y, pz = P.z;
    const int orig = __float_as_int(P.w);

    // block AABB
    float mnx = px, mxx = px, mny = py, mxy = py, mnz = pz, mxz = pz;
    #pragma unroll
    for (int off = 32; off >= 1; off >>= 1) {
        mnx = fminf(mnx, __shfl_xor(mnx, off));
        mxx = fmaxf(mxx, __shfl_xor(mxx, off));
        mny = fminf(mny, __shfl_xor(mny, off));
        mxy = fmaxf(mxy, __shfl_xor(mxy, off));
        mnz = fminf(mnz, __shfl_xor(mnz, off));
        mxz = fmaxf(mxz, __shfl_xor(mxz, off));
    }
    const int wave = tid >> 6;
    if ((tid & 63) == 0) {
        s_min[wave][0] = mnx; s_min[wave][1] = mny; s_min[wave][2] = mnz;
        s_max[wave][0] = mxx; s_max[wave][1] = mxy; s_max[wave][2] = mxz;
    }
    if (tid == 0) s_nact = 0;
    __syncthreads();
    const float bmnx = fminf(fminf(s_min[0][0], s_min[1][0]), fminf(s_min[2][0], s_min[3][0]));
    const float bmny = fminf(fminf(s_min[0][1], s_min[1][1]), fminf(s_min[2][1], s_min[3][1]));
    const float bmnz = fminf(fminf(s_min[0][2], s_min[1][2]), fminf(s_min[2][2], s_min[3][2]));
    const float bmxx = fmaxf(fmaxf(s_max[0][0], s_max[1][0]), fmaxf(s_max[2][0], s_max[3][0]));
    const float bmxy = fmaxf(fmaxf(s_max[0][1], s_max[1][1]), fmaxf(s_max[2][1], s_max[3][1]));
    const float bmxz = fmaxf(fmaxf(s_max[0][2], s_max[1][2]), fmaxf(s_max[2][2], s_max[3][2]));

    // conservative cull (1 thread = 1 gaussian of this segment)
    {
        const int gg = seg * 256 + tid;
        float4 c = gp4[(size_t)gg * 8];
        float ddx = fmaxf(0.f, fmaxf(bmnx - c.x, c.x - bmxx));
        float ddy = fmaxf(0.f, fmaxf(bmny - c.y, c.y - bmxy));
        float ddz = fmaxf(0.f, fmaxf(bmnz - c.z, c.z - bmxz));
        float dd2 = ddx*ddx + ddy*ddy + ddz*ddz;
        if (dd2 <= c.w) {
            int slot = atomicAdd(&s_nact, 1);
            s_act[slot] = gg;
        }
    }
    __syncthreads();
    const int nact = s_nact;

    // stage surviving records into LDS: 8 lanes copy one record's 128 B
    for (int idx = tid; idx < nact * 8; idx += BLOCK) {
        int rec = idx >> 3, q = idx & 7;
        s_rec[idx] = gp4[((size_t)s_act[rec] << 3) + q];
    }
    __syncthreads();

    float opac = 0.f, sig = 0.f;
    for (int j = 0; j < nact; ++j) {
        const float4* R = &s_rec[j * 8];
        float4 q0 = R[0];
        float dx = px - q0.x, dy = py - q0.y, dz = pz - q0.z;
        float d2 = dx*dx + dy*dy + dz*dz;
        if (__all(d2 > q0.w)) continue;          // wave provably negligible

        float4 q1 = R[1], q2 = R[2];
        float vx = q1.x*dx + q1.y*dy + q1.z*dz;
        float vy = q1.y*dx + q1.w*dy + q2.x*dz;
        float vz = q1.z*dx + q2.x*dy + q2.y*dz;
        float maha = dx*vx + dy*vy + dz*vz;      // includes the 0.5
        float w = __expf(q2.z - maha);           // op * exp(-0.5*maha)
        opac += w;

        if (__any(w > 1e-9f)) {
            float4 q3 = R[3], q4 = R[4], q5 = R[5], q6 = R[6];
            float rinv = rsqrtf(d2);
            float x = -dx * rinv, y = -dy * rinv, z = -dz * rinv;
            float xx = x*x, yy = y*y, zz = z*z;
            float xy = x*y, yz = y*z, xz = x*z;

            float res = q3.x;
            res += y * q3.y;
            res += z * q3.z;
            res += x * q3.w;
            res += xy * q4.x;
            res += yz * q4.y;
            res += (3.f*zz - 1.f) * q4.z;
            res += xz * q4.w;
            float xxmyy = xx - yy;
            res += xxmyy * q5.x;
            res += y * (3.f*xx - yy) * q5.y;
            res += (xy * z) * q5.z;
            float f5z1 = 5.f*zz - 1.f;
            res += y * f5z1 * q5.w;
            res += z * (5.f*zz - 3.f) * q6.x;
            res += x * f5z1 * q6.y;
            res += z * xxmyy * q6.z;
            res += x * (xxmyy - 3.f*zz) * q6.w;

            sig += w * fmaxf(res, 0.f);
        }
    }

    // agent-scope partial store (visible across XCDs), then ticket
    F2U u; u.f2 = make_float2(opac, sig);
    __hip_atomic_store(&part[((size_t)(pb * NSPLIT + seg)) * 256 + tid], u.u,
                       __ATOMIC_RELAXED, __HIP_MEMORY_SCOPE_AGENT);
    __threadfence();
    __syncthreads();
    if (tid == 0) {
        int old = atomicAdd(&ticket[pb], 1);
        s_last = (old == NSPLIT - 1);
    }
    __syncthreads();

    if (s_last) {
        __threadfence();
        float o = 0.f, sg = 0.f;
        #pragma unroll
        for (int s = 0; s < NSPLIT; ++s) {
            F2U v;
            v.u = __hip_atomic_load(&part[((size_t)(pb * NSPLIT + s)) * 256 + tid],
                                    __ATOMIC_RELAXED, __HIP_MEMORY_SCOPE_AGENT);
            o += v.f2.x; sg += v.f2.y;
        }
        out[orig] = o;
        out[N_PTS + orig] = sg;
    }
}

extern "C" void kernel_launch(void* const* d_in, const int* in_sizes, int n_in,
                              void* d_out, int out_size, void* d_ws, size_t ws_size,
                              hipStream_t stream) {
    const float* pts      = (const float*)d_in[0];
    const float* xyz      = (const float*)d_in[3];
    const float* sh_dc    = (const float*)d_in[4];
    const float* sh_rest  = (const float*)d_in[5];
    const float* scaling  = (const float*)d_in[6];
    const float* rotation = (const float*)d_in[7];
    const float* opl      = (const float*)d_in[8];

    float*  out    = (float*)d_out;
    float*  wsf    = (float*)d_ws;
    float*  gp     = wsf + WS_GP;
    int*    ticket = (int*)(wsf + WS_TICKET);
    float4* spts   = (float4*)(wsf + WS_SPTS);
    unsigned long long* part = (unsigned long long*)(wsf + WS_PART);

    setup_kernel<<<dim3(1), dim3(1024), 0, stream>>>(
        pts, xyz, sh_dc, sh_rest, scaling, rotation, opl, gp, ticket, spts);

    gauss_kernel<<<dim3(NBLK_PT * NSPLIT), dim3(BLOCK), 0, stream>>>(
        spts, (const float4*)gp, part, ticket, out);
}

// Round 9
// 130.921 us; speedup vs baseline: 2.1889x; 2.1889x over previous
//
#include <hip/hip_runtime.h>
#include <hip/hip_bf16.h>

// ---- problem constants ----
#define N_GAUSS 4096
#define N_PTS   32768
#define BLOCK   256
#define NSPLIT  32                  // 128-gaussian segments; grid 128 x 32
#define SEGSZ   (N_GAUSS / NSPLIT)  // 128
#define NBLK_PT 128                 // 128 x 256 = 32768 points
#define GSTRIDE 28                  // floats per packed gaussian
#define NCELL   4096                // 16^3 morton cells

#define SH_C0  0.28209479177387814f
#define SH_C1  0.4886025119029199f

// Workspace layout (float index):
#define WS_GP     0                          // 4096*28 = 114688 floats
#define WS_GHIST  114688                     // int[4096]
#define WS_CELLID 118784                     // int[32768]
#define WS_SPTS   151552                     // float4[32768] = 131072 floats
#define WS_PART   282624                     // float2[4096*256] = 2097152 floats
// total 2,379,776 floats = 9.52 MB

__device__ __forceinline__ int expand4(int b) {
    return (b & 1) | ((b & 2) << 2) | ((b & 4) << 4) | ((b & 8) << 6);
}

// ---------------------------------------------------------------------------
// D1: blocks 0..15 gaussian prep | 16..143 point cell ids.  (R7-proven)
// ---------------------------------------------------------------------------
__global__ __launch_bounds__(256) void prep_bin_kernel(
    const float* __restrict__ pts, const float* __restrict__ xyz,
    const float* __restrict__ sh_dc, const float* __restrict__ sh_rest,
    const float* __restrict__ scaling, const float* __restrict__ rotation,
    const float* __restrict__ opl, float* __restrict__ gp, int* __restrict__ cellid)
{
    const int tid = threadIdx.x, bx = blockIdx.x;
    if (bx < 16) {
        int g = bx * 256 + tid;
        float s0 = scaling[3*g+0], s1 = scaling[3*g+1], s2 = scaling[3*g+2];
        float i0 = __expf(-2.0f * s0);
        float i1 = __expf(-2.0f * s1);
        float i2 = __expf(-2.0f * s2);
        float maxs2 = __expf(2.0f * fmaxf(s0, fmaxf(s1, s2)));

        float r = rotation[4*g+0], x = rotation[4*g+1];
        float y = rotation[4*g+2], z = rotation[4*g+3];
        float n = rsqrtf(r*r + x*x + y*y + z*z);
        r *= n; x *= n; y *= n; z *= n;
        float R00 = 1.f - 2.f*(y*y + z*z), R01 = 2.f*(x*y - r*z), R02 = 2.f*(x*z + r*y);
        float R10 = 2.f*(x*y + r*z), R11 = 1.f - 2.f*(x*x + z*z), R12 = 2.f*(y*z - r*x);
        float R20 = 2.f*(x*z - r*y), R21 = 2.f*(y*z + r*x), R22 = 1.f - 2.f*(x*x + y*y);

        float pxx = 0.5f*(R00*R00*i0 + R01*R01*i1 + R02*R02*i2);
        float pxy = 0.5f*(R00*R10*i0 + R01*R11*i1 + R02*R12*i2);
        float pxz = 0.5f*(R00*R20*i0 + R01*R21*i1 + R02*R22*i2);
        float pyy = 0.5f*(R10*R10*i0 + R11*R11*i1 + R12*R12*i2);
        float pyz = 0.5f*(R10*R20*i0 + R11*R21*i1 + R12*R22*i2);
        float pzz = 0.5f*(R20*R20*i0 + R21*R21*i1 + R22*R22*i2);

        float op    = 1.f / (1.f + __expf(-opl[g]));
        float lnop  = __logf(op);
        // d2 > Tg => w < e^-16 ~ 1.1e-7; dropped total ~2e-3 << 4.1e-2 threshold
        float Tg    = 2.0f * maxs2 * (lnop + 16.0f);

        float* G = gp + (size_t)g * GSTRIDE;
        G[0] = xyz[3*g+0]; G[1] = xyz[3*g+1]; G[2] = xyz[3*g+2]; G[3] = Tg;
        G[4] = pxx; G[5] = pxy; G[6] = pxz; G[7] = pyy; G[8] = pyz; G[9] = pzz;
        G[10] = lnop; G[11] = 0.f;

        const float* sr = sh_rest + (size_t)g * 15;
        G[12] =  SH_C0 * sh_dc[g];
        G[13] = -SH_C1 * sr[0];
        G[14] =  SH_C1 * sr[1];
        G[15] = -SH_C1 * sr[2];
        G[16] =  1.0925484305920792f  * sr[3];
        G[17] = -1.0925484305920792f  * sr[4];
        G[18] =  0.31539156525252005f * sr[5];
        G[19] = -1.0925484305920792f  * sr[6];
        G[20] =  0.5462742152960396f  * sr[7];
        G[21] = -0.5900435899266435f  * sr[8];
        G[22] =  2.890611442640554f   * sr[9];
        G[23] = -0.4570457994644658f  * sr[10];
        G[24] =  0.3731763325901154f  * sr[11];
        G[25] = -0.4570457994644658f  * sr[12];
        G[26] =  1.445305721320277f   * sr[13];
        G[27] = -0.5900435899266435f  * sr[14];
    } else {
        int p = (bx - 16) * 256 + tid;
        float x = pts[3*p+0], y = pts[3*p+1], z = pts[3*p+2];
        int cx = min(15, max(0, (int)((x + 3.2f) * 2.5f)));
        int cy = min(15, max(0, (int)((y + 3.2f) * 2.5f)));
        int cz = min(15, max(0, (int)((z + 3.2f) * 2.5f)));
        cellid[p] = expand4(cx) | (expand4(cy) << 1) | (expand4(cz) << 2);
    }
}

// ---------------------------------------------------------------------------
// D2: one block: 4096-cell histogram (LDS) + exclusive scan -> offsets.
// ---------------------------------------------------------------------------
__global__ __launch_bounds__(1024) void scan_kernel(
    const int* __restrict__ cellid, int* __restrict__ ghist)
{
    __shared__ int s_hist[NCELL];
    __shared__ int s_scan[1024];
    const int t = threadIdx.x;
    #pragma unroll
    for (int i = 0; i < 4; ++i) s_hist[t + i * 1024] = 0;
    __syncthreads();
    for (int p = t; p < N_PTS; p += 1024) atomicAdd(&s_hist[cellid[p]], 1);
    __syncthreads();
    int b = t * 4;
    int c0 = s_hist[b], c1 = s_hist[b+1], c2 = s_hist[b+2], c3 = s_hist[b+3];
    int s = c0 + c1 + c2 + c3;
    s_scan[t] = s;
    __syncthreads();
    for (int off = 1; off < 1024; off <<= 1) {
        int v = (t >= off) ? s_scan[t - off] : 0;
        __syncthreads();
        s_scan[t] += v;
        __syncthreads();
    }
    int excl = s_scan[t] - s;
    ghist[b]   = excl;
    ghist[b+1] = excl + c0;
    ghist[b+2] = excl + c0 + c1;
    ghist[b+3] = excl + c0 + c1 + c2;
}

// ---------------------------------------------------------------------------
// D3: scatter points into sorted float4 (xyz + bitcast orig index).
// ---------------------------------------------------------------------------
__global__ __launch_bounds__(256) void scatter_kernel(
    const float* __restrict__ pts, const int* __restrict__ cellid,
    int* __restrict__ ghist, float4* __restrict__ spts)
{
    int p = blockIdx.x * 256 + threadIdx.x;
    float x = pts[3*p+0], y = pts[3*p+1], z = pts[3*p+2];
    int pos = atomicAdd(&ghist[cellid[p]], 1);
    spts[pos] = make_float4(x, y, z, __int_as_float(p));
}

// ---------------------------------------------------------------------------
// Eval body for one surviving record (R7-proven math, SH gated by __any).
// ---------------------------------------------------------------------------
__device__ __forceinline__ void eval_one(
    const float* __restrict__ G, float dx, float dy, float dz, float d2,
    float& opac, float& sig)
{
    float vx = G[4]*dx + G[5]*dy + G[6]*dz;
    float vy = G[5]*dx + G[7]*dy + G[8]*dz;
    float vz = G[6]*dx + G[8]*dy + G[9]*dz;
    float maha = dx*vx + dy*vy + dz*vz;      // includes the 0.5
    float w = __expf(G[10] - maha);          // op * exp(-0.5*maha)
    opac += w;

    if (__any(w > 1e-9f)) {
        float rinv = rsqrtf(d2);
        float x = -dx * rinv, y = -dy * rinv, z = -dz * rinv;
        float xx = x*x, yy = y*y, zz = z*z;
        float xy = x*y, yz = y*z, xz = x*z;

        float res = G[12];
        res += y * G[13];
        res += z * G[14];
        res += x * G[15];
        res += xy * G[16];
        res += yz * G[17];
        res += (3.f*zz - 1.f) * G[18];
        res += xz * G[19];
        float xxmyy = xx - yy;
        res += xxmyy * G[20];
        res += y * (3.f*xx - yy) * G[21];
        res += (xy * z) * G[22];
        float f5z1 = 5.f*zz - 1.f;
        res += y * f5z1 * G[23];
        res += z * (5.f*zz - 3.f) * G[24];
        res += x * f5z1 * G[25];
        res += z * xxmyy * G[26];
        res += x * (xxmyy - 3.f*zz) * G[27];

        sig += w * fmaxf(res, 0.f);
    }
}

// ---------------------------------------------------------------------------
// D4: main eval. Block = (256 sorted points) x (128-gaussian segment).
// AABB cull -> LDS list -> 2-way software-pipelined gated loop (both records'
// centers/thresholds loaded before either gate) -> plain partial stores.
// ---------------------------------------------------------------------------
__global__ __launch_bounds__(BLOCK, 4) void gauss_kernel(
    const float4* __restrict__ spts, const float* __restrict__ gp,
    float2* __restrict__ part)
{
    __shared__ float s_min[4][3], s_max[4][3];
    __shared__ int s_nact;
    __shared__ int s_act[SEGSZ];

    const int tid = threadIdx.x;
    const int pb  = blockIdx.x;
    const int seg = blockIdx.y;
    float4 P = spts[pb * 256 + tid];
    const float px = P.x, py = P.y, pz = P.z;

    // block AABB
    float mnx = px, mxx = px, mny = py, mxy = py, mnz = pz, mxz = pz;
    #pragma unroll
    for (int off = 32; off >= 1; off >>= 1) {
        mnx = fminf(mnx, __shfl_xor(mnx, off));
        mxx = fmaxf(mxx, __shfl_xor(mxx, off));
        mny = fminf(mny, __shfl_xor(mny, off));
        mxy = fmaxf(mxy, __shfl_xor(mxy, off));
        mnz = fminf(mnz, __shfl_xor(mnz, off));
        mxz = fmaxf(mxz, __shfl_xor(mxz, off));
    }
    const int wave = tid >> 6;
    if ((tid & 63) == 0) {
        s_min[wave][0] = mnx; s_min[wave][1] = mny; s_min[wave][2] = mnz;
        s_max[wave][0] = mxx; s_max[wave][1] = mxy; s_max[wave][2] = mxz;
    }
    if (tid == 0) s_nact = 0;
    __syncthreads();
    const float bmnx = fminf(fminf(s_min[0][0], s_min[1][0]), fminf(s_min[2][0], s_min[3][0]));
    const float bmny = fminf(fminf(s_min[0][1], s_min[1][1]), fminf(s_min[2][1], s_min[3][1]));
    const float bmnz = fminf(fminf(s_min[0][2], s_min[1][2]), fminf(s_min[2][2], s_min[3][2]));
    const float bmxx = fmaxf(fmaxf(s_max[0][0], s_max[1][0]), fmaxf(s_max[2][0], s_max[3][0]));
    const float bmxy = fmaxf(fmaxf(s_max[0][1], s_max[1][1]), fmaxf(s_max[2][1], s_max[3][1]));
    const float bmxz = fmaxf(fmaxf(s_max[0][2], s_max[1][2]), fmaxf(s_max[2][2], s_max[3][2]));

    // conservative cull: threads 0..127 test this segment's 128 gaussians
    if (tid < SEGSZ) {
        const int gg = seg * SEGSZ + tid;
        const float* Gc = gp + (size_t)gg * GSTRIDE;
        float cx = Gc[0], cy = Gc[1], cz = Gc[2], Tg = Gc[3];
        float ddx = fmaxf(0.f, fmaxf(bmnx - cx, cx - bmxx));
        float ddy = fmaxf(0.f, fmaxf(bmny - cy, cy - bmxy));
        float ddz = fmaxf(0.f, fmaxf(bmnz - cz, cz - bmxz));
        float dd2 = ddx*ddx + ddy*ddy + ddz*ddz;
        if (dd2 <= Tg) {
            int slot = atomicAdd(&s_nact, 1);
            s_act[slot] = gg;
        }
    }
    __syncthreads();
    const int nact = s_nact;

    float opac = 0.f, sig = 0.f;
    for (int j = 0; j < nact; j += 2) {
        const bool has1 = (j + 1 < nact);
        const int g0 = __builtin_amdgcn_readfirstlane(s_act[j]);
        const int g1 = __builtin_amdgcn_readfirstlane(s_act[has1 ? j + 1 : j]);
        const float* __restrict__ A = gp + (size_t)g0 * GSTRIDE;
        const float* __restrict__ B = gp + (size_t)g1 * GSTRIDE;

        // both records' q0 loaded before either gate -> overlapped load chains
        float a0 = A[0], a1 = A[1], a2 = A[2], aT = A[3];
        float b0 = B[0], b1 = B[1], b2 = B[2], bT = B[3];
        float adx = px - a0, ady = py - a1, adz = pz - a2;
        float bdx = px - b0, bdy = py - b1, bdz = pz - b2;
        float ad2 = adx*adx + ady*ady + adz*adz;
        float bd2 = bdx*bdx + bdy*bdy + bdz*bdz;

        if (!__all(ad2 > aT)) eval_one(A, adx, ady, adz, ad2, opac, sig);
        if (has1 && !__all(bd2 > bT)) eval_one(B, bdx, bdy, bdz, bd2, opac, sig);
    }

    part[((size_t)(pb * NSPLIT + seg)) * 256 + tid] = make_float2(opac, sig);
}

// ---------------------------------------------------------------------------
// D5: reduce 32 segment partials per point, write out[orig] once.
// ---------------------------------------------------------------------------
__global__ __launch_bounds__(256) void reduce_kernel(
    const float2* __restrict__ part, const float4* __restrict__ spts,
    float* __restrict__ out)
{
    const int tid = threadIdx.x, pb = blockIdx.x;
    float o = 0.f, sg = 0.f;
    #pragma unroll
    for (int s = 0; s < NSPLIT; ++s) {
        float2 v = part[((size_t)(pb * NSPLIT + s)) * 256 + tid];
        o += v.x; sg += v.y;
    }
    int orig = __float_as_int(spts[pb * 256 + tid].w);
    out[orig] = o;
    out[N_PTS + orig] = sg;
}

extern "C" void kernel_launch(void* const* d_in, const int* in_sizes, int n_in,
                              void* d_out, int out_size, void* d_ws, size_t ws_size,
                              hipStream_t stream) {
    const float* pts      = (const float*)d_in[0];
    const float* xyz      = (const float*)d_in[3];
    const float* sh_dc    = (const float*)d_in[4];
    const float* sh_rest  = (const float*)d_in[5];
    const float* scaling  = (const float*)d_in[6];
    const float* rotation = (const float*)d_in[7];
    const float* opl      = (const float*)d_in[8];

    float*  out    = (float*)d_out;
    float*  wsf    = (float*)d_ws;
    float*  gp     = wsf + WS_GP;
    int*    ghist  = (int*)(wsf + WS_GHIST);
    int*    cellid = (int*)(wsf + WS_CELLID);
    float4* spts   = (float4*)(wsf + WS_SPTS);
    float2* part   = (float2*)(wsf + WS_PART);

    prep_bin_kernel<<<dim3(144), dim3(256), 0, stream>>>(
        pts, xyz, sh_dc, sh_rest, scaling, rotation, opl, gp, cellid);
    scan_kernel<<<dim3(1), dim3(1024), 0, stream>>>(cellid, ghist);
    scatter_kernel<<<dim3(NBLK_PT), dim3(256), 0, stream>>>(pts, cellid, ghist, spts);

    dim3 grid(NBLK_PT, NSPLIT);
    gauss_kernel<<<grid, dim3(BLOCK), 0, stream>>>(spts, gp, part);
    reduce_kernel<<<dim3(NBLK_PT), dim3(256), 0, stream>>>(part, spts, out);
}